// Round 8
// baseline (288.174 us; speedup 1.0000x reference)
//
#include <hip/hip_runtime.h>
#include <hip/hip_bf16.h>

typedef __attribute__((ext_vector_type(8))) short short8;
typedef __attribute__((ext_vector_type(4))) float f32x4;
typedef __attribute__((ext_vector_type(4))) float float4v;

#define NPB 256        // nodes per bucket (dst >> 8)
#define PBLK 256       // partition blocks
#define SCAN_TILE 1024

// ---------------- phase 1: per-(block,bucket) histogram ----------------
__global__ __launch_bounds__(256) void p1_hist(const int* __restrict__ dst,
                                               int* __restrict__ MT, int E, int NB, int chunk) {
    __shared__ int h[512];
    int t = threadIdx.x, p = blockIdx.x;
    for (int i = t; i < NB; i += 256) h[i] = 0;
    __syncthreads();
    int beg = p * chunk, end = min(beg + chunk, E);
    for (int e = beg + t; e < end; e += 256) atomicAdd(&h[dst[e] >> 8], 1);
    __syncthreads();
    for (int b = t; b < NB; b += 256) MT[b * PBLK + p] = h[b];
}

// ---------------- device-wide exclusive scan (1024-elem tiles) ----------------
__global__ __launch_bounds__(256) void scanA_kernel(const int* __restrict__ in,
                                                    int* __restrict__ out,
                                                    int* __restrict__ blocksums, int n) {
    __shared__ int sums[256];
    int t = threadIdx.x;
    int base = blockIdx.x * SCAN_TILE + t * 4;
    int v0 = (base + 0 < n) ? in[base + 0] : 0;
    int v1 = (base + 1 < n) ? in[base + 1] : 0;
    int v2 = (base + 2 < n) ? in[base + 2] : 0;
    int v3 = (base + 3 < n) ? in[base + 3] : 0;
    sums[t] = v0 + v1 + v2 + v3;
    __syncthreads();
    for (int off = 1; off < 256; off <<= 1) {
        int add = (t >= off) ? sums[t - off] : 0;
        __syncthreads();
        sums[t] += add;
        __syncthreads();
    }
    int run = (t == 0) ? 0 : sums[t - 1];
    if (base + 0 < n) out[base + 0] = run; run += v0;
    if (base + 1 < n) out[base + 1] = run; run += v1;
    if (base + 2 < n) out[base + 2] = run; run += v2;
    if (base + 3 < n) out[base + 3] = run;
    if (t == 255) blocksums[blockIdx.x] = sums[255];
}

__global__ __launch_bounds__(256) void scanB_kernel(int* __restrict__ blocksums, int nb) {
    __shared__ int sums[256];
    int t = threadIdx.x;
    sums[t] = (t < nb) ? blocksums[t] : 0;
    __syncthreads();
    for (int off = 1; off < 256; off <<= 1) {
        int add = (t >= off) ? sums[t - off] : 0;
        __syncthreads();
        sums[t] += add;
        __syncthreads();
    }
    if (t < nb) blocksums[t] = (t == 0) ? 0 : sums[t - 1];
}

__global__ __launch_bounds__(256) void scanC_kernel(int* __restrict__ data,
                                                    const int* __restrict__ blocksums, int n) {
    int i = blockIdx.x * 256 + threadIdx.x;
    if (i < n) data[i] += blocksums[i / SCAN_TILE];
}

// ---------------- phase 2: partition edges into buckets (LDS cursors only) ----------------
__global__ __launch_bounds__(256) void p2_part(const int* __restrict__ src,
                                               const int* __restrict__ dst,
                                               const float* __restrict__ ew,
                                               const int* __restrict__ MTs,
                                               int* __restrict__ pp, float* __restrict__ pw,
                                               int E, int NB, int chunk) {
    __shared__ int cur[512];
    int t = threadIdx.x, p = blockIdx.x;
    for (int b = t; b < NB; b += 256) cur[b] = MTs[b * PBLK + p];
    __syncthreads();
    int beg = p * chunk, end = min(beg + chunk, E);
    for (int e = beg + t; e < end; e += 256) {
        int d = dst[e];
        int b = d >> 8;
        int pos = atomicAdd(&cur[b], 1);
        pp[pos] = src[e] | ((d & 255) << 20);   // src < 2^20, dlocal in [0,256)
        pw[pos] = ew[e];
    }
}

// ---------------- phase 3: per-bucket exact CSR + degree + dinv ----------------
__global__ __launch_bounds__(256) void p3_bucket(const int* __restrict__ pp,
                                                 const float* __restrict__ pw,
                                                 const int* __restrict__ MTs,
                                                 int* __restrict__ srcs,
                                                 float* __restrict__ ews,
                                                 int* __restrict__ rowptr,
                                                 float* __restrict__ dinv,
                                                 int E, int N, int NB) {
    __shared__ int cnt[256];
    __shared__ float wd[256];
    __shared__ int ls[256];
    __shared__ int cur[256];
    int t = threadIdx.x, b = blockIdx.x;
    int beg = MTs[b * PBLK];
    int end = (b == NB - 1) ? E : MTs[(b + 1) * PBLK];
    cnt[t] = 0;
    wd[t] = 0.0f;
    __syncthreads();
    for (int e = beg + t; e < end; e += 256) {
        int v = pp[e];
        int dl = v >> 20;
        atomicAdd(&cnt[dl], 1);
        atomicAdd(&wd[dl], pw[e]);
    }
    __syncthreads();
    ls[t] = cnt[t];
    __syncthreads();
    for (int off = 1; off < 256; off <<= 1) {
        int add = (t >= off) ? ls[t - off] : 0;
        __syncthreads();
        ls[t] += add;
        __syncthreads();
    }
    int excl = (t == 0) ? 0 : ls[t - 1];
    int node = b * NPB + t;
    if (node < N) {
        rowptr[node] = beg + excl;
        dinv[node] = rsqrtf(1.0f + wd[t]);   // +1 = self-loop weight
    }
    cur[t] = beg + excl;
    if (b == NB - 1 && t == 0) rowptr[N] = E;
    __syncthreads();
    for (int e = beg + t; e < end; e += 256) {
        int v = pp[e];
        int dl = v >> 20;
        int pos = atomicAdd(&cur[dl], 1);
        srcs[pos] = v & 0xFFFFF;
        ews[pos] = pw[e];
    }
}

// ---------------- split_scale: xs = bf16(dinv .* x) ----------------
__global__ __launch_bounds__(256) void split_scale(const float* __restrict__ x,
                                                   const float* __restrict__ dinv,
                                                   __hip_bfloat16* __restrict__ xs,
                                                   int nquad) {   // nquad = N*32 float4s
    int i = blockIdx.x * 256 + threadIdx.x;
    if (i >= nquad) return;
    float4v v = ((const float4v*)x)[i];
    float s = dinv[i >> 5];   // 32 float4s per 128-col row
    unsigned u0 = (unsigned)__bfloat16_as_ushort(__float2bfloat16(s * v[0]))
                | ((unsigned)__bfloat16_as_ushort(__float2bfloat16(s * v[1])) << 16);
    unsigned u1 = (unsigned)__bfloat16_as_ushort(__float2bfloat16(s * v[2]))
                | ((unsigned)__bfloat16_as_ushort(__float2bfloat16(s * v[3])) << 16);
    uint2 pk = {u0, u1};
    ((uint2*)xs)[i] = pk;
}

// ---------------- aggregation: t = dinv.*(sum ew*F[src] + F[self]), split hi/lo ----------------
// F is pre-scaled bf16 (dinv.*X or dinv.*H). One wave per node, lane = cols 2l,2l+1.
__global__ __launch_bounds__(256) void agg_kernel(const __hip_bfloat16* __restrict__ F,
                                                  const int* __restrict__ rowptr,
                                                  const int* __restrict__ srcs,
                                                  const float* __restrict__ ews,
                                                  const float* __restrict__ dinv,
                                                  unsigned* __restrict__ thiU,
                                                  unsigned* __restrict__ tloU, int n) {
    const unsigned* Fu = (const unsigned*)F;   // one uint = 2 bf16 cols
    int wid  = (blockIdx.x * 256 + threadIdx.x) >> 6;
    int lane = threadIdx.x & 63;
    int node = __builtin_amdgcn_readfirstlane(wid);
    if (node >= n) return;

    int beg = rowptr[node];
    int end = rowptr[node + 1];
    float di = dinv[node];

    unsigned sv = Fu[(size_t)node * 64 + lane];
    float accx = __uint_as_float(sv << 16);
    float accy = __uint_as_float(sv & 0xFFFF0000u);

    int e = beg;
    for (; e + 8 <= end; e += 8) {
        int s_[8];
        float w_[8];
        unsigned v_[8];
#pragma unroll
        for (int j = 0; j < 8; ++j) s_[j] = srcs[e + j];
#pragma unroll
        for (int j = 0; j < 8; ++j) w_[j] = ews[e + j];
#pragma unroll
        for (int j = 0; j < 8; ++j) v_[j] = Fu[(size_t)s_[j] * 64 + lane];
#pragma unroll
        for (int j = 0; j < 8; ++j) {
            accx += w_[j] * __uint_as_float(v_[j] << 16);
            accy += w_[j] * __uint_as_float(v_[j] & 0xFFFF0000u);
        }
    }
    for (; e < end; ++e) {
        int s = srcs[e];
        float w = ews[e];
        unsigned v = Fu[(size_t)s * 64 + lane];
        accx += w * __uint_as_float(v << 16);
        accy += w * __uint_as_float(v & 0xFFFF0000u);
    }

    float t0 = di * accx;
    float t1 = di * accy;
    __hip_bfloat16 h0 = __float2bfloat16(t0);
    __hip_bfloat16 h1 = __float2bfloat16(t1);
    float r0 = t0 - __bfloat162float(h0);
    float r1 = t1 - __bfloat162float(h1);
    unsigned hw = (unsigned)__bfloat16_as_ushort(h0)
                | ((unsigned)__bfloat16_as_ushort(h1) << 16);
    unsigned lw = (unsigned)__bfloat16_as_ushort(__float2bfloat16(r0))
                | ((unsigned)__bfloat16_as_ushort(__float2bfloat16(r1)) << 16);
    thiU[(size_t)node * 64 + lane] = hw;
    tloU[(size_t)node * 64 + lane] = lw;
}

// ---------------- MFMA GEMM on pre-split A: out = relu(A @ W + b) ----------------
// A = Ahi + Alo (bf16 planes); P = Ahi*Whi + Alo*Whi + Ahi*Wlo (split-precision ~ fp32).
// mode 0: outb = bf16(dinv .* relu(..))  (gather input for next layer)
// mode 1: outf = relu(..)                (final fp32 output)
// No conversions in the main loop: A fragments are direct short8 loads.
__global__ __launch_bounds__(256) void gemm_mfma(const __hip_bfloat16* __restrict__ Ahi,
                                                 const __hip_bfloat16* __restrict__ Alo,
                                                 const float* __restrict__ W,
                                                 const float* __restrict__ bias,
                                                 const float* __restrict__ dinv,
                                                 __hip_bfloat16* __restrict__ outb,
                                                 float* __restrict__ outf,
                                                 int nrows, int mode) {
    __shared__ short sWhi[128 * 128];
    __shared__ short sWlo[128 * 128];

    const int t = threadIdx.x;

    // ---- stage whole W: 16 batched float4 loads, hi/lo split, transposed+swizzled ----
    {
        float4v wv[16];
        const float4v* Wg = (const float4v*)W;
#pragma unroll
        for (int j = 0; j < 16; ++j) wv[j] = Wg[t + j * 256];
#pragma unroll
        for (int j = 0; j < 16; ++j) {
            int i4 = (t + j * 256) * 4;
            int k = i4 >> 7;
            int c0 = i4 & 127;
#pragma unroll
            for (int q = 0; q < 4; ++q) {
                int c = c0 + q;
                __hip_bfloat16 h = __float2bfloat16(wv[j][q]);
                float hf = __bfloat162float(h);
                int idx = (c * 128 + k) ^ ((c & 7) << 3);
                sWhi[idx] = (short)__bfloat16_as_ushort(h);
                sWlo[idx] = (short)__bfloat16_as_ushort(__float2bfloat16(wv[j][q] - hf));
            }
        }
    }
    __syncthreads();   // the only barrier

    const int lane = t & 63;
    const int fr = lane & 15;      // frag row/col index
    const int kq = lane >> 4;      // 0..3 -> k sub-offset 8*kq

    float bv[8];
#pragma unroll
    for (int fc = 0; fc < 8; ++fc) bv[fc] = bias[fc * 16 + fr];

    const int gw = blockIdx.x * 4 + (t >> 6);     // global wave id
    const int nw = gridDim.x * 4;
    const int npan = (nrows + 15) / 16;

    for (int p = gw; p < npan; p += nw) {
        const int arow = p * 16 + fr;

        // ---- A fragments: direct short8 loads from pre-split planes ----
        short8 ahi[4], alo[4];
        if (arow < nrows) {
            const __hip_bfloat16* ph = Ahi + (size_t)arow * 128 + kq * 8;
            const __hip_bfloat16* pl = Alo + (size_t)arow * 128 + kq * 8;
#pragma unroll
            for (int ks = 0; ks < 4; ++ks) {
                ahi[ks] = *(const short8*)(ph + ks * 32);
                alo[ks] = *(const short8*)(pl + ks * 32);
            }
        } else {
#pragma unroll
            for (int ks = 0; ks < 4; ++ks) {
                ahi[ks] = (short8){0, 0, 0, 0, 0, 0, 0, 0};
                alo[ks] = (short8){0, 0, 0, 0, 0, 0, 0, 0};
            }
        }

        // ---- compute: 16 rows x 128 cols ----
        f32x4 acc[8];
#pragma unroll
        for (int fc = 0; fc < 8; ++fc) acc[fc] = (f32x4){0.f, 0.f, 0.f, 0.f};

#pragma unroll
        for (int ks = 0; ks < 4; ++ks) {
            int ak = ks * 32 + 8 * kq;
#pragma unroll
            for (int fc = 0; fc < 8; ++fc) {
                int c = fc * 16 + fr;
                int bidx = (c * 128 + ak) ^ ((c & 7) << 3);
                short8 bhi = *(short8*)&sWhi[bidx];
                short8 blo = *(short8*)&sWlo[bidx];
                acc[fc] = __builtin_amdgcn_mfma_f32_16x16x32_bf16(ahi[ks], bhi, acc[fc], 0, 0, 0);
                acc[fc] = __builtin_amdgcn_mfma_f32_16x16x32_bf16(alo[ks], bhi, acc[fc], 0, 0, 0);
                acc[fc] = __builtin_amdgcn_mfma_f32_16x16x32_bf16(ahi[ks], blo, acc[fc], 0, 0, 0);
            }
        }

        // ---- epilogue: relu + bias; mode 0 -> dinv-scaled bf16, mode 1 -> fp32 ----
        int rb = p * 16 + kq * 4;
        if (mode == 0) {
#pragma unroll
            for (int r = 0; r < 4; ++r) {
                int grow = rb + r;
                if (grow < nrows) {
                    float s = dinv[grow];
#pragma unroll
                    for (int fc = 0; fc < 8; ++fc) {
                        float v = fmaxf(acc[fc][r] + bv[fc], 0.0f);
                        outb[(size_t)grow * 128 + fc * 16 + fr] = __float2bfloat16(s * v);
                    }
                }
            }
        } else {
#pragma unroll
            for (int r = 0; r < 4; ++r) {
                int grow = rb + r;
                if (grow < nrows) {
#pragma unroll
                    for (int fc = 0; fc < 8; ++fc) {
                        outf[(size_t)grow * 128 + fc * 16 + fr] = fmaxf(acc[fc][r] + bv[fc], 0.0f);
                    }
                }
            }
        }
    }
}

// ---------------- launcher ----------------

extern "C" void kernel_launch(void* const* d_in, const int* in_sizes, int n_in,
                              void* d_out, int out_size, void* d_ws, size_t ws_size,
                              hipStream_t stream) {
    const float* x  = (const float*)d_in[0];
    const int*   ei = (const int*)d_in[1];
    const float* ew = (const float*)d_in[2];
    const float* W1 = (const float*)d_in[3];
    const float* b1 = (const float*)d_in[4];
    const float* W2 = (const float*)d_in[5];
    const float* b2 = (const float*)d_in[6];
    float* out = (float*)d_out;

    const int N = in_sizes[0] / 128;
    const int E = in_sizes[2];
    const int* src = ei;
    const int* dst = ei + E;

    const int NB = (N + NPB - 1) / NPB;        // buckets (391 for N=100k)
    const int L  = NB * PBLK;                  // count-matrix length
    const int chunk = (E + PBLK - 1) / PBLK;

    // workspace layout
    __hip_bfloat16* gat = (__hip_bfloat16*)d_ws;          // N*128 bf16 (gather features)
    __hip_bfloat16* thi = gat + (size_t)N * 128;          // N*128 bf16 (t hi plane)
    __hip_bfloat16* tlo = thi + (size_t)N * 128;          // N*128 bf16 (t lo plane)
    int*   srcs   = (int*)(tlo + (size_t)N * 128);        // E
    float* ews    = (float*)(srcs + E);        // E
    int*   rowptr = (int*)(ews + E);           // N+1
    float* dinv   = (float*)(rowptr + N + 1);  // N
    int*   MT     = (int*)(dinv + N);          // L
    int*   MTs    = MT + L;                    // L
    int*   bsums  = MTs + L;                   // ceil(L/1024)
    int*   pp     = (int*)thi;                 // alias (E ints, dead before thi written)
    float* pw     = (float*)tlo;               // alias (E floats, dead before tlo written)

    const int nb_scan = (L + SCAN_TILE - 1) / SCAN_TILE;

    hipLaunchKernelGGL(p1_hist, dim3(PBLK), dim3(256), 0, stream, dst, MT, E, NB, chunk);
    hipLaunchKernelGGL(scanA_kernel, dim3(nb_scan), dim3(256), 0, stream, MT, MTs, bsums, L);
    hipLaunchKernelGGL(scanB_kernel, dim3(1), dim3(256), 0, stream, bsums, nb_scan);
    hipLaunchKernelGGL(scanC_kernel, dim3((L + 255) / 256), dim3(256), 0, stream, MTs, bsums, L);
    hipLaunchKernelGGL(p2_part, dim3(PBLK), dim3(256), 0, stream, src, dst, ew, MTs, pp, pw, E, NB, chunk);
    hipLaunchKernelGGL(p3_bucket, dim3(NB), dim3(256), 0, stream, pp, pw, MTs, srcs, ews, rowptr, dinv, E, N, NB);

    // xs = bf16(dinv .* x) -> gat
    hipLaunchKernelGGL(split_scale, dim3((N * 32 + 255) / 256), dim3(256), 0, stream,
                       x, dinv, gat, N * 32);

    // layer 1: t1 = dinv.*(agg(gat)) -> (thi,tlo) ; h1s = bf16(dinv.*relu(t1@W1+b1)) -> gat
    hipLaunchKernelGGL(agg_kernel, dim3((N + 3) / 4), dim3(256), 0, stream,
                       gat, rowptr, srcs, ews, dinv, (unsigned*)thi, (unsigned*)tlo, N);
    hipLaunchKernelGGL(gemm_mfma, dim3(512), dim3(256), 0, stream,
                       thi, tlo, W1, b1, dinv, gat, (float*)nullptr, N, 0);

    // layer 2: t2 = dinv.*(agg(gat)) -> (thi,tlo) ; out = relu(t2@W2+b2) -> d_out
    hipLaunchKernelGGL(agg_kernel, dim3((N + 3) / 4), dim3(256), 0, stream,
                       gat, rowptr, srcs, ews, dinv, (unsigned*)thi, (unsigned*)tlo, N);
    hipLaunchKernelGGL(gemm_mfma, dim3(512), dim3(256), 0, stream,
                       thi, tlo, W2, b2, dinv, (__hip_bfloat16*)nullptr, out, N, 1);
}

// Round 9
// 260.200 us; speedup vs baseline: 1.1075x; 1.1075x over previous
//
#include <hip/hip_runtime.h>
#include <hip/hip_bf16.h>

typedef __attribute__((ext_vector_type(8))) short short8;
typedef __attribute__((ext_vector_type(4))) float f32x4;
typedef __attribute__((ext_vector_type(4))) float float4v;

#define NPB 256        // nodes per bucket (dst >> 8)
#define PBLK 256       // partition blocks
#define SCAN_TILE 1024

// ---------------- phase 1: per-(block,bucket) histogram ----------------
__global__ __launch_bounds__(256) void p1_hist(const int* __restrict__ dst,
                                               int* __restrict__ MT, int E, int NB, int chunk) {
    __shared__ int h[512];
    int t = threadIdx.x, p = blockIdx.x;
    for (int i = t; i < NB; i += 256) h[i] = 0;
    __syncthreads();
    int beg = p * chunk, end = min(beg + chunk, E);
    for (int e = beg + t; e < end; e += 256) atomicAdd(&h[dst[e] >> 8], 1);
    __syncthreads();
    for (int b = t; b < NB; b += 256) MT[b * PBLK + p] = h[b];
}

// ---------------- device-wide exclusive scan (1024-elem tiles) ----------------
__global__ __launch_bounds__(256) void scanA_kernel(const int* __restrict__ in,
                                                    int* __restrict__ out,
                                                    int* __restrict__ blocksums, int n) {
    __shared__ int sums[256];
    int t = threadIdx.x;
    int base = blockIdx.x * SCAN_TILE + t * 4;
    int v0 = (base + 0 < n) ? in[base + 0] : 0;
    int v1 = (base + 1 < n) ? in[base + 1] : 0;
    int v2 = (base + 2 < n) ? in[base + 2] : 0;
    int v3 = (base + 3 < n) ? in[base + 3] : 0;
    sums[t] = v0 + v1 + v2 + v3;
    __syncthreads();
    for (int off = 1; off < 256; off <<= 1) {
        int add = (t >= off) ? sums[t - off] : 0;
        __syncthreads();
        sums[t] += add;
        __syncthreads();
    }
    int run = (t == 0) ? 0 : sums[t - 1];
    if (base + 0 < n) out[base + 0] = run; run += v0;
    if (base + 1 < n) out[base + 1] = run; run += v1;
    if (base + 2 < n) out[base + 2] = run; run += v2;
    if (base + 3 < n) out[base + 3] = run;
    if (t == 255) blocksums[blockIdx.x] = sums[255];
}

__global__ __launch_bounds__(256) void scanB_kernel(int* __restrict__ blocksums, int nb) {
    __shared__ int sums[256];
    int t = threadIdx.x;
    sums[t] = (t < nb) ? blocksums[t] : 0;
    __syncthreads();
    for (int off = 1; off < 256; off <<= 1) {
        int add = (t >= off) ? sums[t - off] : 0;
        __syncthreads();
        sums[t] += add;
        __syncthreads();
    }
    if (t < nb) blocksums[t] = (t == 0) ? 0 : sums[t - 1];
}

__global__ __launch_bounds__(256) void scanC_kernel(int* __restrict__ data,
                                                    const int* __restrict__ blocksums, int n) {
    int i = blockIdx.x * 256 + threadIdx.x;
    if (i < n) data[i] += blocksums[i / SCAN_TILE];
}

// ---------------- phase 2: partition edges into buckets (LDS cursors only) ----------------
__global__ __launch_bounds__(256) void p2_part(const int* __restrict__ src,
                                               const int* __restrict__ dst,
                                               const float* __restrict__ ew,
                                               const int* __restrict__ MTs,
                                               int* __restrict__ pp, float* __restrict__ pw,
                                               int E, int NB, int chunk) {
    __shared__ int cur[512];
    int t = threadIdx.x, p = blockIdx.x;
    for (int b = t; b < NB; b += 256) cur[b] = MTs[b * PBLK + p];
    __syncthreads();
    int beg = p * chunk, end = min(beg + chunk, E);
    for (int e = beg + t; e < end; e += 256) {
        int d = dst[e];
        int b = d >> 8;
        int pos = atomicAdd(&cur[b], 1);
        pp[pos] = src[e] | ((d & 255) << 20);   // src < 2^20, dlocal in [0,256)
        pw[pos] = ew[e];
    }
}

// ---------------- phase 3: per-bucket exact CSR + degree + dinv ----------------
__global__ __launch_bounds__(256) void p3_bucket(const int* __restrict__ pp,
                                                 const float* __restrict__ pw,
                                                 const int* __restrict__ MTs,
                                                 int* __restrict__ srcs,
                                                 float* __restrict__ ews,
                                                 int* __restrict__ rowptr,
                                                 float* __restrict__ dinv,
                                                 int E, int N, int NB) {
    __shared__ int cnt[256];
    __shared__ float wd[256];
    __shared__ int ls[256];
    __shared__ int cur[256];
    int t = threadIdx.x, b = blockIdx.x;
    int beg = MTs[b * PBLK];
    int end = (b == NB - 1) ? E : MTs[(b + 1) * PBLK];
    cnt[t] = 0;
    wd[t] = 0.0f;
    __syncthreads();
    for (int e = beg + t; e < end; e += 256) {
        int v = pp[e];
        int dl = v >> 20;
        atomicAdd(&cnt[dl], 1);
        atomicAdd(&wd[dl], pw[e]);
    }
    __syncthreads();
    ls[t] = cnt[t];
    __syncthreads();
    for (int off = 1; off < 256; off <<= 1) {
        int add = (t >= off) ? ls[t - off] : 0;
        __syncthreads();
        ls[t] += add;
        __syncthreads();
    }
    int excl = (t == 0) ? 0 : ls[t - 1];
    int node = b * NPB + t;
    if (node < N) {
        rowptr[node] = beg + excl;
        dinv[node] = rsqrtf(1.0f + wd[t]);   // +1 = self-loop weight
    }
    cur[t] = beg + excl;
    if (b == NB - 1 && t == 0) rowptr[N] = E;
    __syncthreads();
    for (int e = beg + t; e < end; e += 256) {
        int v = pp[e];
        int dl = v >> 20;
        int pos = atomicAdd(&cur[dl], 1);
        srcs[pos] = v & 0xFFFFF;
        ews[pos] = pw[e];
    }
}

// ---------------- split_scale: xs = bf16(dinv .* x) ----------------
__global__ __launch_bounds__(256) void split_scale(const float* __restrict__ x,
                                                   const float* __restrict__ dinv,
                                                   __hip_bfloat16* __restrict__ xs,
                                                   int nquad) {   // nquad = N*32 float4s
    int i = blockIdx.x * 256 + threadIdx.x;
    if (i >= nquad) return;
    float4v v = ((const float4v*)x)[i];
    float s = dinv[i >> 5];   // 32 float4s per 128-col row
    unsigned u0 = (unsigned)__bfloat16_as_ushort(__float2bfloat16(s * v[0]))
                | ((unsigned)__bfloat16_as_ushort(__float2bfloat16(s * v[1])) << 16);
    unsigned u1 = (unsigned)__bfloat16_as_ushort(__float2bfloat16(s * v[2]))
                | ((unsigned)__bfloat16_as_ushort(__float2bfloat16(s * v[3])) << 16);
    uint2 pk = {u0, u1};
    ((uint2*)xs)[i] = pk;
}

// ---------------- aggregation: t = dinv.*(sum ew*F[src] + F[self]), split hi/lo ----------------
__global__ __launch_bounds__(256) void agg_kernel(const __hip_bfloat16* __restrict__ F,
                                                  const int* __restrict__ rowptr,
                                                  const int* __restrict__ srcs,
                                                  const float* __restrict__ ews,
                                                  const float* __restrict__ dinv,
                                                  unsigned* __restrict__ thiU,
                                                  unsigned* __restrict__ tloU, int n) {
    const unsigned* Fu = (const unsigned*)F;   // one uint = 2 bf16 cols
    int wid  = (blockIdx.x * 256 + threadIdx.x) >> 6;
    int lane = threadIdx.x & 63;
    int node = __builtin_amdgcn_readfirstlane(wid);
    if (node >= n) return;

    int beg = rowptr[node];
    int end = rowptr[node + 1];
    float di = dinv[node];

    unsigned sv = Fu[(size_t)node * 64 + lane];
    float accx = __uint_as_float(sv << 16);
    float accy = __uint_as_float(sv & 0xFFFF0000u);

    int e = beg;
    for (; e + 8 <= end; e += 8) {
        int s_[8];
        float w_[8];
        unsigned v_[8];
#pragma unroll
        for (int j = 0; j < 8; ++j) s_[j] = srcs[e + j];
#pragma unroll
        for (int j = 0; j < 8; ++j) w_[j] = ews[e + j];
#pragma unroll
        for (int j = 0; j < 8; ++j) v_[j] = Fu[(size_t)s_[j] * 64 + lane];
#pragma unroll
        for (int j = 0; j < 8; ++j) {
            accx += w_[j] * __uint_as_float(v_[j] << 16);
            accy += w_[j] * __uint_as_float(v_[j] & 0xFFFF0000u);
        }
    }
    for (; e < end; ++e) {
        int s = srcs[e];
        float w = ews[e];
        unsigned v = Fu[(size_t)s * 64 + lane];
        accx += w * __uint_as_float(v << 16);
        accy += w * __uint_as_float(v & 0xFFFF0000u);
    }

    float t0 = di * accx;
    float t1 = di * accy;
    __hip_bfloat16 h0 = __float2bfloat16(t0);
    __hip_bfloat16 h1 = __float2bfloat16(t1);
    float r0 = t0 - __bfloat162float(h0);
    float r1 = t1 - __bfloat162float(h1);
    unsigned hw = (unsigned)__bfloat16_as_ushort(h0)
                | ((unsigned)__bfloat16_as_ushort(h1) << 16);
    unsigned lw = (unsigned)__bfloat16_as_ushort(__float2bfloat16(r0))
                | ((unsigned)__bfloat16_as_ushort(__float2bfloat16(r1)) << 16);
    thiU[(size_t)node * 64 + lane] = hw;
    tloU[(size_t)node * 64 + lane] = lw;
}

// ---------------- MFMA GEMM, 64-row wave tiles: out = relu(A @ W + b) ----------------
// A = Ahi + Alo (bf16 planes); P = Ahi*Whi + Alo*Whi + Ahi*Wlo (split-precision ~ fp32).
// One 64x128 panel per wave (npan = ceil(N/64) waves). Each B-fragment LDS read
// feeds 4 MFMAs (4x less LDS traffic than 16-row tiles). A k-slices ping-pong
// double-buffered, statically indexed. W staged coalesced: lanes read consecutive
// W columns, write transposed hi/lo planes via ds_write_b128.
// mode 0: outb = bf16(dinv .* relu(..));  mode 1: outf = relu(..)
__global__ __launch_bounds__(256, 2) void gemm_mfma(const __hip_bfloat16* __restrict__ Ahi,
                                                    const __hip_bfloat16* __restrict__ Alo,
                                                    const float* __restrict__ W,
                                                    const float* __restrict__ bias,
                                                    const float* __restrict__ dinv,
                                                    __hip_bfloat16* __restrict__ outb,
                                                    float* __restrict__ outf,
                                                    int nrows, int mode) {
    __shared__ short sWhi[128 * 128];
    __shared__ short sWlo[128 * 128];

    const int t = threadIdx.x;

    // ---- stage W transposed [c][k]: coalesced reads, b128 LDS writes ----
    {
        const int c = t & 127;
        const int kg0 = t >> 7;   // 0..1
#pragma unroll
        for (int it = 0; it < 8; ++it) {
            int kg = kg0 + it * 2;   // 0..15
            float wv[8];
#pragma unroll
            for (int j = 0; j < 8; ++j) wv[j] = W[(size_t)(kg * 8 + j) * 128 + c];
            short8 h8, l8;
#pragma unroll
            for (int j = 0; j < 8; ++j) {
                __hip_bfloat16 h = __float2bfloat16(wv[j]);
                h8[j] = (short)__bfloat16_as_ushort(h);
                l8[j] = (short)__bfloat16_as_ushort(__float2bfloat16(wv[j] - __bfloat162float(h)));
            }
            int idx = (c * 128 + kg * 8) ^ ((c & 7) << 3);
            *(short8*)&sWhi[idx] = h8;
            *(short8*)&sWlo[idx] = l8;
        }
    }
    __syncthreads();   // the only barrier

    const int lane = t & 63;
    const int fr = lane & 15;      // frag row/col index
    const int kq = lane >> 4;      // 0..3 -> k sub-offset 8*kq

    const int wid = blockIdx.x * 4 + (t >> 6);      // one 64-row panel per wave
    const int npan = (nrows + 63) >> 6;
    if (wid >= npan) return;
    const int r0 = wid * 64;

    float bv[8];
#pragma unroll
    for (int fc = 0; fc < 8; ++fc) bv[fc] = bias[fc * 16 + fr];

    const short8 z8 = {0, 0, 0, 0, 0, 0, 0, 0};

#define LOADA(KS, AH, AL)                                                     \
    {                                                                         \
        _Pragma("unroll")                                                     \
        for (int rf_ = 0; rf_ < 4; ++rf_) {                                   \
            int row_ = r0 + rf_ * 16 + fr;                                    \
            if (row_ < nrows) {                                               \
                size_t off_ = (size_t)row_ * 128 + (KS) * 32 + kq * 8;        \
                AH[rf_] = *(const short8*)(Ahi + off_);                       \
                AL[rf_] = *(const short8*)(Alo + off_);                       \
            } else {                                                          \
                AH[rf_] = z8;                                                 \
                AL[rf_] = z8;                                                 \
            }                                                                 \
        }                                                                     \
    }

#define KSTEP(KS, AH, AL)                                                     \
    {                                                                         \
        _Pragma("unroll")                                                     \
        for (int fc_ = 0; fc_ < 8; ++fc_) {                                   \
            int c_ = fc_ * 16 + fr;                                           \
            int bidx_ = (c_ * 128 + (KS) * 32 + kq * 8) ^ ((c_ & 7) << 3);    \
            short8 bhi_ = *(short8*)&sWhi[bidx_];                             \
            short8 blo_ = *(short8*)&sWlo[bidx_];                             \
            _Pragma("unroll")                                                 \
            for (int rf_ = 0; rf_ < 4; ++rf_) {                               \
                acc[rf_][fc_] = __builtin_amdgcn_mfma_f32_16x16x32_bf16(      \
                    AH[rf_], bhi_, acc[rf_][fc_], 0, 0, 0);                   \
                acc[rf_][fc_] = __builtin_amdgcn_mfma_f32_16x16x32_bf16(      \
                    AL[rf_], bhi_, acc[rf_][fc_], 0, 0, 0);                   \
                acc[rf_][fc_] = __builtin_amdgcn_mfma_f32_16x16x32_bf16(      \
                    AH[rf_], blo_, acc[rf_][fc_], 0, 0, 0);                   \
            }                                                                 \
        }                                                                     \
    }

    f32x4 acc[4][8];
#pragma unroll
    for (int rf = 0; rf < 4; ++rf)
#pragma unroll
        for (int fc = 0; fc < 8; ++fc) acc[rf][fc] = (f32x4){0.f, 0.f, 0.f, 0.f};

    short8 ahA[4], alA[4], ahB[4], alB[4];
    LOADA(0, ahA, alA);
    LOADA(1, ahB, alB);
    KSTEP(0, ahA, alA);
    LOADA(2, ahA, alA);
    KSTEP(1, ahB, alB);
    LOADA(3, ahB, alB);
    KSTEP(2, ahA, alA);
    KSTEP(3, ahB, alB);

#undef LOADA
#undef KSTEP

    // ---- epilogue: relu + bias; mode 0 -> dinv-scaled bf16, mode 1 -> fp32 ----
    if (mode == 0) {
#pragma unroll
        for (int rf = 0; rf < 4; ++rf) {
            int rb = r0 + rf * 16 + kq * 4;
#pragma unroll
            for (int r = 0; r < 4; ++r) {
                int grow = rb + r;
                if (grow < nrows) {
                    float s = dinv[grow];
#pragma unroll
                    for (int fc = 0; fc < 8; ++fc) {
                        float v = fmaxf(acc[rf][fc][r] + bv[fc], 0.0f);
                        outb[(size_t)grow * 128 + fc * 16 + fr] = __float2bfloat16(s * v);
                    }
                }
            }
        }
    } else {
#pragma unroll
        for (int rf = 0; rf < 4; ++rf) {
            int rb = r0 + rf * 16 + kq * 4;
#pragma unroll
            for (int r = 0; r < 4; ++r) {
                int grow = rb + r;
                if (grow < nrows) {
#pragma unroll
                    for (int fc = 0; fc < 8; ++fc) {
                        outf[(size_t)grow * 128 + fc * 16 + fr] =
                            fmaxf(acc[rf][fc][r] + bv[fc], 0.0f);
                    }
                }
            }
        }
    }
}

// ---------------- launcher ----------------

extern "C" void kernel_launch(void* const* d_in, const int* in_sizes, int n_in,
                              void* d_out, int out_size, void* d_ws, size_t ws_size,
                              hipStream_t stream) {
    const float* x  = (const float*)d_in[0];
    const int*   ei = (const int*)d_in[1];
    const float* ew = (const float*)d_in[2];
    const float* W1 = (const float*)d_in[3];
    const float* b1 = (const float*)d_in[4];
    const float* W2 = (const float*)d_in[5];
    const float* b2 = (const float*)d_in[6];
    float* out = (float*)d_out;

    const int N = in_sizes[0] / 128;
    const int E = in_sizes[2];
    const int* src = ei;
    const int* dst = ei + E;

    const int NB = (N + NPB - 1) / NPB;        // buckets (391 for N=100k)
    const int L  = NB * PBLK;                  // count-matrix length
    const int chunk = (E + PBLK - 1) / PBLK;

    // workspace layout
    __hip_bfloat16* gat = (__hip_bfloat16*)d_ws;          // N*128 bf16 (gather features)
    __hip_bfloat16* thi = gat + (size_t)N * 128;          // N*128 bf16 (t hi plane)
    __hip_bfloat16* tlo = thi + (size_t)N * 128;          // N*128 bf16 (t lo plane)
    int*   srcs   = (int*)(tlo + (size_t)N * 128);        // E
    float* ews    = (float*)(srcs + E);        // E
    int*   rowptr = (int*)(ews + E);           // N+1
    float* dinv   = (float*)(rowptr + N + 1);  // N
    int*   MT     = (int*)(dinv + N);          // L
    int*   MTs    = MT + L;                    // L
    int*   bsums  = MTs + L;                   // ceil(L/1024)
    int*   pp     = (int*)thi;                 // alias (E ints, dead before thi written)
    float* pw     = (float*)tlo;               // alias (E floats, dead before tlo written)

    const int nb_scan = (L + SCAN_TILE - 1) / SCAN_TILE;
    const int npan = (N + 63) / 64;
    const int gblocks = (npan + 3) / 4;

    hipLaunchKernelGGL(p1_hist, dim3(PBLK), dim3(256), 0, stream, dst, MT, E, NB, chunk);
    hipLaunchKernelGGL(scanA_kernel, dim3(nb_scan), dim3(256), 0, stream, MT, MTs, bsums, L);
    hipLaunchKernelGGL(scanB_kernel, dim3(1), dim3(256), 0, stream, bsums, nb_scan);
    hipLaunchKernelGGL(scanC_kernel, dim3((L + 255) / 256), dim3(256), 0, stream, MTs, bsums, L);
    hipLaunchKernelGGL(p2_part, dim3(PBLK), dim3(256), 0, stream, src, dst, ew, MTs, pp, pw, E, NB, chunk);
    hipLaunchKernelGGL(p3_bucket, dim3(NB), dim3(256), 0, stream, pp, pw, MTs, srcs, ews, rowptr, dinv, E, N, NB);

    // xs = bf16(dinv .* x) -> gat
    hipLaunchKernelGGL(split_scale, dim3((N * 32 + 255) / 256), dim3(256), 0, stream,
                       x, dinv, gat, N * 32);

    // layer 1: t1 = dinv.*(agg(gat)) -> (thi,tlo) ; gat = bf16(dinv.*relu(t1@W1+b1))
    hipLaunchKernelGGL(agg_kernel, dim3((N + 3) / 4), dim3(256), 0, stream,
                       gat, rowptr, srcs, ews, dinv, (unsigned*)thi, (unsigned*)tlo, N);
    hipLaunchKernelGGL(gemm_mfma, dim3(gblocks), dim3(256), 0, stream,
                       thi, tlo, W1, b1, dinv, gat, (float*)nullptr, N, 0);

    // layer 2: t2 = dinv.*(agg(gat)) -> (thi,tlo) ; out = relu(t2@W2+b2)
    hipLaunchKernelGGL(agg_kernel, dim3((N + 3) / 4), dim3(256), 0, stream,
                       gat, rowptr, srcs, ews, dinv, (unsigned*)thi, (unsigned*)tlo, N);
    hipLaunchKernelGGL(gemm_mfma, dim3(gblocks), dim3(256), 0, stream,
                       thi, tlo, W2, b2, dinv, (__hip_bfloat16*)nullptr, out, N, 1);
}

// Round 10
// 242.322 us; speedup vs baseline: 1.1892x; 1.0738x over previous
//
#include <hip/hip_runtime.h>
#include <hip/hip_bf16.h>

typedef __attribute__((ext_vector_type(8))) _Float16 half8;
typedef __attribute__((ext_vector_type(4))) float f32x4;
typedef __attribute__((ext_vector_type(4))) float float4v;

#define NPB 256        // nodes per bucket (dst >> 8)
#define PBLK 256       // partition blocks
#define SCAN_TILE 1024

// ---------------- phase 1: per-(block,bucket) histogram ----------------
__global__ __launch_bounds__(256) void p1_hist(const int* __restrict__ dst,
                                               int* __restrict__ MT, int E, int NB, int chunk) {
    __shared__ int h[512];
    int t = threadIdx.x, p = blockIdx.x;
    for (int i = t; i < NB; i += 256) h[i] = 0;
    __syncthreads();
    int beg = p * chunk, end = min(beg + chunk, E);
    for (int e = beg + t; e < end; e += 256) atomicAdd(&h[dst[e] >> 8], 1);
    __syncthreads();
    for (int b = t; b < NB; b += 256) MT[b * PBLK + p] = h[b];
}

// ---------------- device-wide exclusive scan (1024-elem tiles) ----------------
__global__ __launch_bounds__(256) void scanA_kernel(const int* __restrict__ in,
                                                    int* __restrict__ out,
                                                    int* __restrict__ blocksums, int n) {
    __shared__ int sums[256];
    int t = threadIdx.x;
    int base = blockIdx.x * SCAN_TILE + t * 4;
    int v0 = (base + 0 < n) ? in[base + 0] : 0;
    int v1 = (base + 1 < n) ? in[base + 1] : 0;
    int v2 = (base + 2 < n) ? in[base + 2] : 0;
    int v3 = (base + 3 < n) ? in[base + 3] : 0;
    sums[t] = v0 + v1 + v2 + v3;
    __syncthreads();
    for (int off = 1; off < 256; off <<= 1) {
        int add = (t >= off) ? sums[t - off] : 0;
        __syncthreads();
        sums[t] += add;
        __syncthreads();
    }
    int run = (t == 0) ? 0 : sums[t - 1];
    if (base + 0 < n) out[base + 0] = run; run += v0;
    if (base + 1 < n) out[base + 1] = run; run += v1;
    if (base + 2 < n) out[base + 2] = run; run += v2;
    if (base + 3 < n) out[base + 3] = run;
    if (t == 255) blocksums[blockIdx.x] = sums[255];
}

__global__ __launch_bounds__(256) void scanB_kernel(int* __restrict__ blocksums, int nb) {
    __shared__ int sums[256];
    int t = threadIdx.x;
    sums[t] = (t < nb) ? blocksums[t] : 0;
    __syncthreads();
    for (int off = 1; off < 256; off <<= 1) {
        int add = (t >= off) ? sums[t - off] : 0;
        __syncthreads();
        sums[t] += add;
        __syncthreads();
    }
    if (t < nb) blocksums[t] = (t == 0) ? 0 : sums[t - 1];
}

__global__ __launch_bounds__(256) void scanC_kernel(int* __restrict__ data,
                                                    const int* __restrict__ blocksums, int n) {
    int i = blockIdx.x * 256 + threadIdx.x;
    if (i < n) data[i] += blocksums[i / SCAN_TILE];
}

// ---------------- phase 2: partition edges into buckets (LDS cursors only) ----------------
__global__ __launch_bounds__(256) void p2_part(const int* __restrict__ src,
                                               const int* __restrict__ dst,
                                               const float* __restrict__ ew,
                                               const int* __restrict__ MTs,
                                               int* __restrict__ pp, float* __restrict__ pw,
                                               int E, int NB, int chunk) {
    __shared__ int cur[512];
    int t = threadIdx.x, p = blockIdx.x;
    for (int b = t; b < NB; b += 256) cur[b] = MTs[b * PBLK + p];
    __syncthreads();
    int beg = p * chunk, end = min(beg + chunk, E);
    for (int e = beg + t; e < end; e += 256) {
        int d = dst[e];
        int b = d >> 8;
        int pos = atomicAdd(&cur[b], 1);
        pp[pos] = src[e] | ((d & 255) << 20);   // src < 2^20, dlocal in [0,256)
        pw[pos] = ew[e];
    }
}

// ---------------- phase 3: per-bucket exact CSR + degree + dinv ----------------
__global__ __launch_bounds__(256) void p3_bucket(const int* __restrict__ pp,
                                                 const float* __restrict__ pw,
                                                 const int* __restrict__ MTs,
                                                 int* __restrict__ srcs,
                                                 float* __restrict__ ews,
                                                 int* __restrict__ rowptr,
                                                 float* __restrict__ dinv,
                                                 int E, int N, int NB) {
    __shared__ int cnt[256];
    __shared__ float wd[256];
    __shared__ int ls[256];
    __shared__ int cur[256];
    int t = threadIdx.x, b = blockIdx.x;
    int beg = MTs[b * PBLK];
    int end = (b == NB - 1) ? E : MTs[(b + 1) * PBLK];
    cnt[t] = 0;
    wd[t] = 0.0f;
    __syncthreads();
    for (int e = beg + t; e < end; e += 256) {
        int v = pp[e];
        int dl = v >> 20;
        atomicAdd(&cnt[dl], 1);
        atomicAdd(&wd[dl], pw[e]);
    }
    __syncthreads();
    ls[t] = cnt[t];
    __syncthreads();
    for (int off = 1; off < 256; off <<= 1) {
        int add = (t >= off) ? ls[t - off] : 0;
        __syncthreads();
        ls[t] += add;
        __syncthreads();
    }
    int excl = (t == 0) ? 0 : ls[t - 1];
    int node = b * NPB + t;
    if (node < N) {
        rowptr[node] = beg + excl;
        dinv[node] = rsqrtf(1.0f + wd[t]);   // +1 = self-loop weight
    }
    cur[t] = beg + excl;
    if (b == NB - 1 && t == 0) rowptr[N] = E;
    __syncthreads();
    for (int e = beg + t; e < end; e += 256) {
        int v = pp[e];
        int dl = v >> 20;
        int pos = atomicAdd(&cur[dl], 1);
        srcs[pos] = v & 0xFFFFF;
        ews[pos] = pw[e];
    }
}

// ---------------- split_scale: xs = fp16(dinv .* x) ----------------
__global__ __launch_bounds__(256) void split_scale(const float* __restrict__ x,
                                                   const float* __restrict__ dinv,
                                                   _Float16* __restrict__ xs,
                                                   int nquad) {   // nquad = N*32 float4s
    int i = blockIdx.x * 256 + threadIdx.x;
    if (i >= nquad) return;
    float4v v = ((const float4v*)x)[i];
    float s = dinv[i >> 5];   // 32 float4s per 128-col row
    union { uint2 u; _Float16 h[4]; } o;
    o.h[0] = (_Float16)(s * v[0]);
    o.h[1] = (_Float16)(s * v[1]);
    o.h[2] = (_Float16)(s * v[2]);
    o.h[3] = (_Float16)(s * v[3]);
    ((uint2*)xs)[i] = o.u;
}

// ---------------- aggregation: t = fp16(dinv.*(sum ew*F[src] + F[self])) ----------------
// F is pre-scaled fp16 (dinv.*X or dinv.*H). One wave per node, lane = cols 2l,2l+1.
__global__ __launch_bounds__(256) void agg_kernel(const _Float16* __restrict__ F,
                                                  const int* __restrict__ rowptr,
                                                  const int* __restrict__ srcs,
                                                  const float* __restrict__ ews,
                                                  const float* __restrict__ dinv,
                                                  unsigned* __restrict__ ttU, int n) {
    const unsigned* Fu = (const unsigned*)F;   // one uint = 2 fp16 cols
    int wid  = (blockIdx.x * 256 + threadIdx.x) >> 6;
    int lane = threadIdx.x & 63;
    int node = __builtin_amdgcn_readfirstlane(wid);
    if (node >= n) return;

    int beg = rowptr[node];
    int end = rowptr[node + 1];
    float di = dinv[node];

    union { unsigned u; _Float16 h[2]; } cv;
    cv.u = Fu[(size_t)node * 64 + lane];
    float accx = (float)cv.h[0];
    float accy = (float)cv.h[1];

    int e = beg;
    for (; e + 8 <= end; e += 8) {
        int s_[8];
        float w_[8];
        unsigned v_[8];
#pragma unroll
        for (int j = 0; j < 8; ++j) s_[j] = srcs[e + j];
#pragma unroll
        for (int j = 0; j < 8; ++j) w_[j] = ews[e + j];
#pragma unroll
        for (int j = 0; j < 8; ++j) v_[j] = Fu[(size_t)s_[j] * 64 + lane];
#pragma unroll
        for (int j = 0; j < 8; ++j) {
            cv.u = v_[j];
            accx += w_[j] * (float)cv.h[0];
            accy += w_[j] * (float)cv.h[1];
        }
    }
    for (; e < end; ++e) {
        int s = srcs[e];
        float w = ews[e];
        cv.u = Fu[(size_t)s * 64 + lane];
        accx += w * (float)cv.h[0];
        accy += w * (float)cv.h[1];
    }

    union { unsigned u; _Float16 h[2]; } o;
    o.h[0] = (_Float16)(di * accx);
    o.h[1] = (_Float16)(di * accy);
    ttU[(size_t)node * 64 + lane] = o.u;
}

// ---------------- MFMA GEMM (fp16): out = relu(A @ W + b) ----------------
// A fp16 single plane; W staged fp16 in LDS (32 KB, transposed+swizzled).
// 32-row wave panels (one per wave), acc 64 VGPR, 3 blocks/CU.
// mode 0: outb = fp16(dinv .* relu(..));  mode 1: outf = relu(..)
__global__ __launch_bounds__(256, 3) void gemm_mfma(const _Float16* __restrict__ A,
                                                    const float* __restrict__ W,
                                                    const float* __restrict__ bias,
                                                    const float* __restrict__ dinv,
                                                    _Float16* __restrict__ outb,
                                                    float* __restrict__ outf,
                                                    int nrows, int mode) {
    __shared__ _Float16 sW[128 * 128];   // [c][k], swizzled

    const int t = threadIdx.x;

    // ---- stage W transposed [c][k]: coalesced reads, b128 LDS writes ----
    {
        const int c = t & 127;
        const int kg0 = t >> 7;   // 0..1
#pragma unroll
        for (int it = 0; it < 8; ++it) {
            int kg = kg0 + it * 2;   // 0..15
            half8 h8;
#pragma unroll
            for (int j = 0; j < 8; ++j)
                h8[j] = (_Float16)W[(size_t)(kg * 8 + j) * 128 + c];
            int idx = (c * 128 + kg * 8) ^ ((c & 7) << 3);
            *(half8*)&sW[idx] = h8;
        }
    }
    __syncthreads();   // the only barrier

    const int lane = t & 63;
    const int fr = lane & 15;      // frag row/col index
    const int kq = lane >> 4;      // 0..3 -> k sub-offset 8*kq

    const int wid = blockIdx.x * 4 + (t >> 6);      // one 32-row panel per wave
    const int npan = (nrows + 31) >> 5;
    if (wid >= npan) return;
    const int r0 = wid * 32;

    float bv[8];
#pragma unroll
    for (int fc = 0; fc < 8; ++fc) bv[fc] = bias[fc * 16 + fr];

    const half8 z8 = {0, 0, 0, 0, 0, 0, 0, 0};

#define LOADA(KS, AH)                                                         \
    {                                                                         \
        _Pragma("unroll")                                                     \
        for (int rf_ = 0; rf_ < 2; ++rf_) {                                   \
            int row_ = r0 + rf_ * 16 + fr;                                    \
            if (row_ < nrows) {                                               \
                AH[rf_] = *(const half8*)(A + (size_t)row_ * 128 + (KS) * 32 + kq * 8); \
            } else {                                                          \
                AH[rf_] = z8;                                                 \
            }                                                                 \
        }                                                                     \
    }

#define KSTEP(KS, AH)                                                         \
    {                                                                         \
        _Pragma("unroll")                                                     \
        for (int fc_ = 0; fc_ < 8; ++fc_) {                                   \
            int c_ = fc_ * 16 + fr;                                           \
            int bidx_ = (c_ * 128 + (KS) * 32 + kq * 8) ^ ((c_ & 7) << 3);    \
            half8 b_ = *(half8*)&sW[bidx_];                                   \
            _Pragma("unroll")                                                 \
            for (int rf_ = 0; rf_ < 2; ++rf_) {                               \
                acc[rf_][fc_] = __builtin_amdgcn_mfma_f32_16x16x32_f16(       \
                    AH[rf_], b_, acc[rf_][fc_], 0, 0, 0);                     \
            }                                                                 \
        }                                                                     \
    }

    f32x4 acc[2][8];
#pragma unroll
    for (int rf = 0; rf < 2; ++rf)
#pragma unroll
        for (int fc = 0; fc < 8; ++fc) acc[rf][fc] = (f32x4){0.f, 0.f, 0.f, 0.f};

    half8 aA[2], aB[2];
    LOADA(0, aA);
    LOADA(1, aB);
    KSTEP(0, aA);
    LOADA(2, aA);
    KSTEP(1, aB);
    LOADA(3, aB);
    KSTEP(2, aA);
    KSTEP(3, aB);

#undef LOADA
#undef KSTEP

    // ---- epilogue: relu + bias; mode 0 -> dinv-scaled fp16, mode 1 -> fp32 ----
    if (mode == 0) {
#pragma unroll
        for (int rf = 0; rf < 2; ++rf) {
            int rb = r0 + rf * 16 + kq * 4;
#pragma unroll
            for (int r = 0; r < 4; ++r) {
                int grow = rb + r;
                if (grow < nrows) {
                    float s = dinv[grow];
#pragma unroll
                    for (int fc = 0; fc < 8; ++fc) {
                        float v = fmaxf(acc[rf][fc][r] + bv[fc], 0.0f);
                        outb[(size_t)grow * 128 + fc * 16 + fr] = (_Float16)(s * v);
                    }
                }
            }
        }
    } else {
#pragma unroll
        for (int rf = 0; rf < 2; ++rf) {
            int rb = r0 + rf * 16 + kq * 4;
#pragma unroll
            for (int r = 0; r < 4; ++r) {
                int grow = rb + r;
                if (grow < nrows) {
#pragma unroll
                    for (int fc = 0; fc < 8; ++fc) {
                        outf[(size_t)grow * 128 + fc * 16 + fr] =
                            fmaxf(acc[rf][fc][r] + bv[fc], 0.0f);
                    }
                }
            }
        }
    }
}

// ---------------- launcher ----------------

extern "C" void kernel_launch(void* const* d_in, const int* in_sizes, int n_in,
                              void* d_out, int out_size, void* d_ws, size_t ws_size,
                              hipStream_t stream) {
    const float* x  = (const float*)d_in[0];
    const int*   ei = (const int*)d_in[1];
    const float* ew = (const float*)d_in[2];
    const float* W1 = (const float*)d_in[3];
    const float* b1 = (const float*)d_in[4];
    const float* W2 = (const float*)d_in[5];
    const float* b2 = (const float*)d_in[6];
    float* out = (float*)d_out;

    const int N = in_sizes[0] / 128;
    const int E = in_sizes[2];
    const int* src = ei;
    const int* dst = ei + E;

    const int NB = (N + NPB - 1) / NPB;        // buckets (391 for N=100k)
    const int L  = NB * PBLK;                  // count-matrix length
    const int chunk = (E + PBLK - 1) / PBLK;

    // workspace layout
    _Float16* gat = (_Float16*)d_ws;                      // N*128 fp16 (gather features)
    _Float16* tt  = gat + (size_t)N * 128;                // N*128 fp16 (agg result t)
    int*   srcs   = (int*)(tt + (size_t)N * 128);         // E
    float* ews    = (float*)(srcs + E);        // E
    int*   rowptr = (int*)(ews + E);           // N+1
    float* dinv   = (float*)(rowptr + N + 1);  // N
    int*   MT     = (int*)(dinv + N);          // L
    int*   MTs    = MT + L;                    // L
    int*   bsums  = MTs + L;                   // ceil(L/1024)
    int*   pp     = (int*)gat;                 // alias (E ints, dead before gat written)
    float* pw     = (float*)tt;                // alias (E floats, dead before tt written)

    const int nb_scan = (L + SCAN_TILE - 1) / SCAN_TILE;
    const int npan = (N + 31) / 32;
    const int gblocks = (npan + 3) / 4;

    hipLaunchKernelGGL(p1_hist, dim3(PBLK), dim3(256), 0, stream, dst, MT, E, NB, chunk);
    hipLaunchKernelGGL(scanA_kernel, dim3(nb_scan), dim3(256), 0, stream, MT, MTs, bsums, L);
    hipLaunchKernelGGL(scanB_kernel, dim3(1), dim3(256), 0, stream, bsums, nb_scan);
    hipLaunchKernelGGL(scanC_kernel, dim3((L + 255) / 256), dim3(256), 0, stream, MTs, bsums, L);
    hipLaunchKernelGGL(p2_part, dim3(PBLK), dim3(256), 0, stream, src, dst, ew, MTs, pp, pw, E, NB, chunk);
    hipLaunchKernelGGL(p3_bucket, dim3(NB), dim3(256), 0, stream, pp, pw, MTs, srcs, ews, rowptr, dinv, E, N, NB);

    // xs = fp16(dinv .* x) -> gat
    hipLaunchKernelGGL(split_scale, dim3((N * 32 + 255) / 256), dim3(256), 0, stream,
                       x, dinv, gat, N * 32);

    // layer 1: t1 = fp16(dinv.*agg(gat)) -> tt ; gat = fp16(dinv.*relu(t1@W1+b1))
    hipLaunchKernelGGL(agg_kernel, dim3((N + 3) / 4), dim3(256), 0, stream,
                       gat, rowptr, srcs, ews, dinv, (unsigned*)tt, N);
    hipLaunchKernelGGL(gemm_mfma, dim3(gblocks), dim3(256), 0, stream,
                       tt, W1, b1, dinv, gat, (float*)nullptr, N, 0);

    // layer 2: t2 = fp16(dinv.*agg(gat)) -> tt ; out = relu(t2@W2+b2)
    hipLaunchKernelGGL(agg_kernel, dim3((N + 3) / 4), dim3(256), 0, stream,
                       gat, rowptr, srcs, ews, dinv, (unsigned*)tt, N);
    hipLaunchKernelGGL(gemm_mfma, dim3(gblocks), dim3(256), 0, stream,
                       tt, W2, b2, dinv, (_Float16*)nullptr, out, N, 1);
}